// Round 1
// baseline (486.628 us; speedup 1.0000x reference)
//
#include <hip/hip_runtime.h>

// FeatureMatchSimpleLoss: B=128, P=512, D=384, GAMMA=20, LAMBDA_INV=25
// Phase 1: per (b,p) masked row-max + argmax of z[b] @ z[b]^T  (fp32 VALU GEMM)
// Phase 2a: per-1024-chunk local top-20
// Phase 2b: merge 64*20 candidates -> global top-20 -> loss + avg_cos

#define NB 128
#define NP 512
#define ND 384
#define NGAMMA 20

#define BM 128
#define BN 64
#define BK 32
#define NQT (NP / BN)   // 8
#define NKT (ND / BK)   // 12
#define NTILES (NQT * NKT)

__global__ __launch_bounds__(256) void fm_phase1(
    const float* __restrict__ z, const int* __restrict__ view,
    float* __restrict__ bval, int* __restrict__ bidx)
{
    // k-major LDS tiles; pads keep rows 16B-aligned (132*4, 68*4 are mult of 16)
    __shared__ __align__(16) float As[BK][BM + 4];
    __shared__ __align__(16) float Bs[BK][BN + 4];
    __shared__ int vs[NP];

    const int tid = threadIdx.x;
    const int b   = blockIdx.x >> 2;
    const int p0  = (blockIdx.x & 3) * BM;
    const int ty  = tid >> 4;   // 0..15 -> 8 rows each
    const int tx  = tid & 15;   // 0..15 -> 4 cols each

    const float* zb = z + (size_t)b * NP * ND;

    vs[tid]       = view[tid];
    vs[tid + 256] = view[tid + 256];
    __syncthreads();

    int rv[8];
#pragma unroll
    for (int i = 0; i < 8; ++i) rv[i] = vs[p0 + ty * 8 + i];

    float best[8];
    int bj[8];
#pragma unroll
    for (int i = 0; i < 8; ++i) { best[i] = -1e30f; bj[i] = 0; }

    float4 pa[4], pb[2];

    // prefetch tile 0 (qt=0, kt=0)
#pragma unroll
    for (int i = 0; i < 4; ++i) {
        int s = tid + 256 * i, r = s >> 3, kg = s & 7;
        pa[i] = *(const float4*)&zb[(p0 + r) * ND + kg * 4];
    }
#pragma unroll
    for (int i = 0; i < 2; ++i) {
        int s = tid + 256 * i, r = s >> 3, kg = s & 7;
        pb[i] = *(const float4*)&zb[r * ND + kg * 4];
    }

    float acc[8][4];

    for (int T = 0; T < NTILES; ++T) {
        const int kt = T % NKT;
        const int qt = T / NKT;
        if (kt == 0) {
#pragma unroll
            for (int i = 0; i < 8; ++i)
#pragma unroll
                for (int j = 0; j < 4; ++j) acc[i][j] = 0.f;
        }
        __syncthreads();  // previous compute done, LDS free
        // transpose-store prefetched regs -> LDS (b32 writes, ~<=4-way conflicts)
#pragma unroll
        for (int i = 0; i < 4; ++i) {
            int s = tid + 256 * i, r = s >> 3, kg = s & 7;
            As[kg * 4 + 0][r] = pa[i].x;
            As[kg * 4 + 1][r] = pa[i].y;
            As[kg * 4 + 2][r] = pa[i].z;
            As[kg * 4 + 3][r] = pa[i].w;
        }
#pragma unroll
        for (int i = 0; i < 2; ++i) {
            int s = tid + 256 * i, r = s >> 3, kg = s & 7;
            Bs[kg * 4 + 0][r] = pb[i].x;
            Bs[kg * 4 + 1][r] = pb[i].y;
            Bs[kg * 4 + 2][r] = pb[i].z;
            Bs[kg * 4 + 3][r] = pb[i].w;
        }
        // issue next tile's global loads; they land during the compute phase
        if (T + 1 < NTILES) {
            const int ktn = (T + 1) % NKT;
            const int qtn = (T + 1) / NKT;
            const int k0n = ktn * BK;
            const int q0n = qtn * BN;
#pragma unroll
            for (int i = 0; i < 4; ++i) {
                int s = tid + 256 * i, r = s >> 3, kg = s & 7;
                pa[i] = *(const float4*)&zb[(p0 + r) * ND + k0n + kg * 4];
            }
#pragma unroll
            for (int i = 0; i < 2; ++i) {
                int s = tid + 256 * i, r = s >> 3, kg = s & 7;
                pb[i] = *(const float4*)&zb[(q0n + r) * ND + k0n + kg * 4];
            }
        }
        __syncthreads();  // LDS tile visible

        // 8x4 register-tile fp32 GEMM; VALU-bound (32 fma vs 3 ds_read_b128 per k)
#pragma unroll 8
        for (int k = 0; k < BK; ++k) {
            float4 a0 = *(const float4*)&As[k][ty * 8];
            float4 a1 = *(const float4*)&As[k][ty * 8 + 4];
            float4 bv = *(const float4*)&Bs[k][tx * 4];
            float av[8] = {a0.x, a0.y, a0.z, a0.w, a1.x, a1.y, a1.z, a1.w};
            float bw[4] = {bv.x, bv.y, bv.z, bv.w};
#pragma unroll
            for (int i = 0; i < 8; ++i)
#pragma unroll
                for (int j = 0; j < 4; ++j)
                    acc[i][j] = fmaf(av[i], bw[j], acc[i][j]);
        }

        if (kt == NKT - 1) {
            // masked running max/argmax. view-mask alone subsumes ~eye
            // (self-pair always same view). masked value = -1.0 like the ref.
            const int q0 = qt * BN;
            int cv[4];
#pragma unroll
            for (int j = 0; j < 4; ++j) cv[j] = vs[q0 + tx * 4 + j];
#pragma unroll
            for (int i = 0; i < 8; ++i) {
#pragma unroll
                for (int j = 0; j < 4; ++j) {
                    float v = (cv[j] != rv[i]) ? acc[i][j] : -1.0f;
                    int q = q0 + tx * 4 + j;
                    if (v > best[i]) { best[i] = v; bj[i] = q; }  // strict > keeps first max
                }
            }
        }
    }

    // reduce across the 16 tx lanes (xor 1,2,4,8 stays inside the tx group)
#pragma unroll
    for (int i = 0; i < 8; ++i) {
        float v = best[i];
        int id = bj[i];
#pragma unroll
        for (int off = 1; off < 16; off <<= 1) {
            float ov = __shfl_xor(v, off);
            int oi = __shfl_xor(id, off);
            if (ov > v || (ov == v && oi < id)) { v = ov; id = oi; }
        }
        if (tx == 0) {
            int p = p0 + ty * 8 + i;
            bval[b * NP + p] = v;
            bidx[b * NP + p] = b * NP + id;  // flat (best_j + b*P)
        }
    }
}

// ---- Phase 2a: each block finds local top-20 of its 1024 values ----
__global__ __launch_bounds__(256) void fm_topk_local(
    const float* __restrict__ bval, float* __restrict__ cval, int* __restrict__ cidx)
{
    __shared__ float sv[1024];
    __shared__ int   si[1024];
    __shared__ float wv[4];
    __shared__ int   wi[4];

    const int t = threadIdx.x;
    const int base = blockIdx.x * 1024;
#pragma unroll
    for (int i = 0; i < 4; ++i) {
        int e = t + 256 * i;
        sv[e] = bval[base + e];
        si[e] = base + e;
    }
    __syncthreads();

    const int lane = t & 63, w = t >> 6;
    for (int it = 0; it < NGAMMA; ++it) {
        float v = sv[t];
        int pos = t;
#pragma unroll
        for (int i = 1; i < 4; ++i) {
            int e = t + 256 * i;
            float x = sv[e];
            if (x > v || (x == v && e < pos)) { v = x; pos = e; }
        }
#pragma unroll
        for (int off = 1; off < 64; off <<= 1) {
            float ov = __shfl_xor(v, off);
            int op = __shfl_xor(pos, off);
            if (ov > v || (ov == v && op < pos)) { v = ov; pos = op; }
        }
        if (lane == 0) { wv[w] = v; wi[w] = pos; }
        __syncthreads();
        if (t == 0) {
            float bv2 = wv[0];
            int bp = wi[0];
            for (int k = 1; k < 4; ++k)
                if (wv[k] > bv2 || (wv[k] == bv2 && wi[k] < bp)) { bv2 = wv[k]; bp = wi[k]; }
            cval[blockIdx.x * NGAMMA + it] = bv2;
            cidx[blockIdx.x * NGAMMA + it] = si[bp];
            sv[bp] = -1e30f;
        }
        __syncthreads();
    }
}

// ---- Phase 2b: merge 1280 candidates -> top-20 -> loss + avg_cos ----
__global__ __launch_bounds__(256) void fm_final(
    const float* __restrict__ cval, const int* __restrict__ cidx,
    const int* __restrict__ bidx, const float* __restrict__ z,
    float* __restrict__ out)
{
    __shared__ float sv[1280];
    __shared__ int   si[1280];
    __shared__ float wv[4];
    __shared__ int   wi[4];
    __shared__ int   sel[NGAMMA];
    __shared__ float ssum;
    __shared__ float red[4];

    const int t = threadIdx.x;
    for (int e = t; e < 1280; e += 256) { sv[e] = cval[e]; si[e] = cidx[e]; }
    if (t == 0) ssum = 0.f;
    __syncthreads();

    const int lane = t & 63, w = t >> 6;
    for (int it = 0; it < NGAMMA; ++it) {
        float v = sv[t];
        int pos = t;
        for (int e = t + 256; e < 1280; e += 256) {
            float x = sv[e];
            if (x > v || (x == v && e < pos)) { v = x; pos = e; }
        }
#pragma unroll
        for (int off = 1; off < 64; off <<= 1) {
            float ov = __shfl_xor(v, off);
            int op = __shfl_xor(pos, off);
            if (ov > v || (ov == v && op < pos)) { v = ov; pos = op; }
        }
        if (lane == 0) { wv[w] = v; wi[w] = pos; }
        __syncthreads();
        if (t == 0) {
            float bv2 = wv[0];
            int bp = wi[0];
            for (int k = 1; k < 4; ++k)
                if (wv[k] > bv2 || (wv[k] == bv2 && wi[k] < bp)) { bv2 = wv[k]; bp = wi[k]; }
            sel[it] = si[bp];
            ssum += bv2;
            sv[bp] = -1e30f;
        }
        __syncthreads();
    }

    // loss = 25 * mean((z1 - z2)^2) over 20 x 384
    float acc = 0.f;
    for (int pr = 0; pr < NGAMMA; ++pr) {
        const int a = sel[pr];
        const int j = bidx[a];
        const float* za = z + (size_t)a * ND;
        const float* zj = z + (size_t)j * ND;
        for (int d = t; d < ND; d += 256) {
            float df = za[d] - zj[d];
            acc = fmaf(df, df, acc);
        }
    }
#pragma unroll
    for (int off = 1; off < 64; off <<= 1) acc += __shfl_xor(acc, off);
    if (lane == 0) red[w] = acc;
    __syncthreads();
    if (t == 0) {
        float tot = red[0] + red[1] + red[2] + red[3];
        out[0] = 25.0f * tot / (float)(NGAMMA * ND);
        out[1] = ssum / (float)NGAMMA;
    }
}

extern "C" void kernel_launch(void* const* d_in, const int* in_sizes, int n_in,
                              void* d_out, int out_size, void* d_ws, size_t ws_size,
                              hipStream_t stream)
{
    const float* z    = (const float*)d_in[0];
    const int*   view = (const int*)d_in[1];
    float*       out  = (float*)d_out;

    // workspace layout: 64K best_sim f32 | 64K best_j i32 | 1280 cand f32 | 1280 cand i32
    char* ws = (char*)d_ws;
    float* ws_val = (float*)ws;
    int*   ws_idx = (int*)(ws + (size_t)NB * NP * 4);
    float* cval   = (float*)(ws + (size_t)NB * NP * 8);
    int*   cidx   = (int*)(ws + (size_t)NB * NP * 8 + 64 * NGAMMA * 4);

    fm_phase1<<<NB * (NP / BM), 256, 0, stream>>>(z, view, ws_val, ws_idx);
    fm_topk_local<<<(NB * NP) / 1024, 256, 0, stream>>>(ws_val, cval, cidx);
    fm_final<<<1, 256, 0, stream>>>(cval, cidx, ws_idx, z, out);
}

// Round 2
// 218.273 us; speedup vs baseline: 2.2294x; 2.2294x over previous
//
#include <hip/hip_runtime.h>

// FeatureMatchSimpleLoss: B=128, P=512, D=384, GAMMA=20, LAMBDA_INV=25
// R2: split-bf16 MFMA path.
//   fm_convert: z(fp32) -> z_hi, z_lo (bf16 RNE split)
//   fm_gemm:    per (b, 128x128 tile): S = A*B^T via 3 MFMA products
//               (hi*hi + hi*lo + lo*hi), fused masked row-max/argmax partials
//   fm_combine: merge 4 column-block partials per (b,p)
//   fm_topk_local / fm_final: unchanged from R1 (global top-20 -> loss, avg cos)
// Fallback to R1 fp32 path if ws_size too small.

#define NB 128
#define NP 512
#define ND 384
#define NGAMMA 20

typedef __attribute__((ext_vector_type(8))) short short8;
typedef __attribute__((ext_vector_type(4))) float f32x4;

__device__ __forceinline__ unsigned short f2bf(float f) {
    unsigned int u = __float_as_uint(f);
    u += 0x7fffu + ((u >> 16) & 1u);   // RNE
    return (unsigned short)(u >> 16);
}
__device__ __forceinline__ float bf2f(unsigned short h) {
    return __uint_as_float(((unsigned int)h) << 16);
}

__device__ __forceinline__ void gload16(const void* gptr, void* lptr) {
    __builtin_amdgcn_global_load_lds(
        (const __attribute__((address_space(1))) void*)gptr,
        (__attribute__((address_space(3))) void*)lptr, 16, 0, 0);
}

// ---- convert: 8 floats/thread -> 8 bf16 hi + 8 bf16 lo ----
__global__ __launch_bounds__(256) void fm_convert(
    const float* __restrict__ z, unsigned short* __restrict__ zhi,
    unsigned short* __restrict__ zlo)
{
    size_t i = (size_t)blockIdx.x * 256 + threadIdx.x;  // 3145728 threads
    const float4* zp = (const float4*)z + i * 2;
    float4 v0 = zp[0], v1 = zp[1];
    float f[8] = {v0.x, v0.y, v0.z, v0.w, v1.x, v1.y, v1.z, v1.w};
    ushort4 h0, h1, l0, l1;
    unsigned short h[8], lo[8];
#pragma unroll
    for (int j = 0; j < 8; ++j) {
        h[j]  = f2bf(f[j]);
        lo[j] = f2bf(f[j] - bf2f(h[j]));
    }
    h0 = make_ushort4(h[0], h[1], h[2], h[3]);
    h1 = make_ushort4(h[4], h[5], h[6], h[7]);
    l0 = make_ushort4(lo[0], lo[1], lo[2], lo[3]);
    l1 = make_ushort4(lo[4], lo[5], lo[6], lo[7]);
    *(ushort4*)&zhi[i * 8]     = h0;
    *(ushort4*)&zhi[i * 8 + 4] = h1;
    *(ushort4*)&zlo[i * 8]     = l0;
    *(ushort4*)&zlo[i * 8 + 4] = l1;
}

// ---- MFMA GEMM + fused masked max/argmax partials ----
// LDS tiles layout [kg][row][8] bf16: ds_read_b128 fragment reads conflict-free,
// global_load_lds staging writes linear (wave-uniform base + lane*16).
__global__ __launch_bounds__(256) void fm_gemm(
    const unsigned short* __restrict__ zhi, const unsigned short* __restrict__ zlo,
    const int* __restrict__ view,
    float* __restrict__ pval, int* __restrict__ pidx)
{
    __shared__ __align__(16) unsigned short Ah[4][128][8];
    __shared__ __align__(16) unsigned short Al[4][128][8];
    __shared__ __align__(16) unsigned short Bh[4][128][8];
    __shared__ __align__(16) unsigned short Bl[4][128][8];
    __shared__ int vs[NP];
    __shared__ float lsv[2][2][64];
    __shared__ int   lsi[2][2][64];

    const int tid  = threadIdx.x;
    const int lane = tid & 63;
    const int wid  = tid >> 6;
    const int wr   = wid >> 1, wc = wid & 1;
    const int g    = lane >> 4, r = lane & 15;

    // XCD-aware swizzle: all 16 blocks of a batch land on one XCD (round-robin)
    const int bid    = blockIdx.x;           // 2048 blocks
    const int xcd    = bid & 7;
    const int t      = bid >> 3;             // 0..255
    const int sub    = t & 15;
    const int bgrp   = t >> 4;               // 0..15
    const int b      = bgrp * 8 + xcd;       // bijective batch id
    const int rowblk = sub >> 2, colblk = sub & 3;
    const int p0 = rowblk * 128, q0 = colblk * 128;

    vs[tid]       = view[tid];
    vs[tid + 256] = view[tid + 256];

    const size_t zb = (size_t)b * NP * ND;

    f32x4 acc[4][4];
#pragma unroll
    for (int mi = 0; mi < 4; ++mi)
#pragma unroll
        for (int ni = 0; ni < 4; ++ni) acc[mi][ni] = (f32x4){0.f, 0.f, 0.f, 0.f};

    for (int kt = 0; kt < ND / 32; ++kt) {
        __syncthreads();   // previous compute done (and vs ready on kt=0)
        // stage: wave wid fills chunks c = 2*wid, 2*wid+1 of each tile (1 KB each)
#pragma unroll
        for (int ci = 0; ci < 2; ++ci) {
            const int c   = wid * 2 + ci;
            const int kg  = c >> 1;                 // uniform per chunk
            const int row = (c & 1) * 64 + lane;    // per-lane
            const size_t ka = zb + (size_t)(p0 + row) * ND + kt * 32 + kg * 8;
            const size_t kb = zb + (size_t)(q0 + row) * ND + kt * 32 + kg * 8;
            gload16(zhi + ka, (char*)Ah + c * 1024);
            gload16(zlo + ka, (char*)Al + c * 1024);
            gload16(zhi + kb, (char*)Bh + c * 1024);
            gload16(zlo + kb, (char*)Bl + c * 1024);
        }
        __syncthreads();   // drains vmcnt -> tiles visible

        short8 ah[4], al[4], bh[4], bl[4];
#pragma unroll
        for (int mi = 0; mi < 4; ++mi) {
            ah[mi] = *(const short8*)&Ah[g][wr * 64 + mi * 16 + r][0];
            al[mi] = *(const short8*)&Al[g][wr * 64 + mi * 16 + r][0];
        }
#pragma unroll
        for (int ni = 0; ni < 4; ++ni) {
            bh[ni] = *(const short8*)&Bh[g][wc * 64 + ni * 16 + r][0];
            bl[ni] = *(const short8*)&Bl[g][wc * 64 + ni * 16 + r][0];
        }
#pragma unroll
        for (int mi = 0; mi < 4; ++mi)
#pragma unroll
            for (int ni = 0; ni < 4; ++ni) {
                acc[mi][ni] = __builtin_amdgcn_mfma_f32_16x16x32_bf16(ah[mi], bh[ni], acc[mi][ni], 0, 0, 0);
                acc[mi][ni] = __builtin_amdgcn_mfma_f32_16x16x32_bf16(ah[mi], bl[ni], acc[mi][ni], 0, 0, 0);
                acc[mi][ni] = __builtin_amdgcn_mfma_f32_16x16x32_bf16(al[mi], bh[ni], acc[mi][ni], 0, 0, 0);
            }
    }

    // masked row-max/argmax over this block's 128 columns.
    // C/D layout (m89): col = lane&15, row = (lane>>4)*4 + reg
#pragma unroll
    for (int mi = 0; mi < 4; ++mi) {
#pragma unroll
        for (int j = 0; j < 4; ++j) {
            const int prow = p0 + wr * 64 + mi * 16 + g * 4 + j;
            const int rv = vs[prow];
            float bv = -2.0f; int bq = 0;
#pragma unroll
            for (int ni = 0; ni < 4; ++ni) {
                const int q = q0 + wc * 64 + ni * 16 + r;
                const float v = (vs[q] != rv) ? acc[mi][ni][j] : -1.0f;  // view mask subsumes ~eye
                if (v > bv) { bv = v; bq = q; }   // strict > keeps smallest q
            }
#pragma unroll
            for (int off = 1; off < 16; off <<= 1) {   // reduce over the 16 col-lanes
                const float ov = __shfl_xor(bv, off);
                const int   oq = __shfl_xor(bq, off);
                if (ov > bv || (ov == bv && oq < bq)) { bv = ov; bq = oq; }
            }
            if (r == 0) {
                lsv[wr][wc][mi * 16 + g * 4 + j] = bv;
                lsi[wr][wc][mi * 16 + g * 4 + j] = bq;
            }
        }
    }
    __syncthreads();
    if (tid < 128) {
        const int w2 = tid >> 6, row = tid & 63;
        float v0 = lsv[w2][0][row]; int i0 = lsi[w2][0][row];
        const float v1 = lsv[w2][1][row]; const int i1 = lsi[w2][1][row];
        if (v1 > v0) { v0 = v1; i0 = i1; }   // tie keeps wc=0 (smaller q)
        const int p = p0 + w2 * 64 + row;
        pval[((size_t)b * NP + p) * 4 + colblk] = v0;
        pidx[((size_t)b * NP + p) * 4 + colblk] = i0;
    }
}

// ---- combine 4 column-block partials per (b,p) ----
__global__ __launch_bounds__(256) void fm_combine(
    const float* __restrict__ pval, const int* __restrict__ pidx,
    float* __restrict__ bval, int* __restrict__ bidx)
{
    const int i = blockIdx.x * 256 + threadIdx.x;   // 65536
    float bv = -2.f; int bq = 0;
#pragma unroll
    for (int c = 0; c < 4; ++c) {   // ascending c = ascending q; strict > keeps first
        const float v = pval[(size_t)i * 4 + c];
        const int q = pidx[(size_t)i * 4 + c];
        if (v > bv) { bv = v; bq = q; }
    }
    bval[i] = bv;
    bidx[i] = ((i >> 9) << 9) + bq;   // flat b*512 + q
}

// ---- R1 fp32 fallback phase 1 (used only if ws too small) ----
#define BM 128
#define BN 64
#define BK 32
#define NQT (NP / BN)
#define NKT (ND / BK)
#define NTILES (NQT * NKT)

__global__ __launch_bounds__(256) void fm_phase1(
    const float* __restrict__ z, const int* __restrict__ view,
    float* __restrict__ bval, int* __restrict__ bidx)
{
    __shared__ __align__(16) float As[BK][BM + 4];
    __shared__ __align__(16) float Bs[BK][BN + 4];
    __shared__ int vs[NP];

    const int tid = threadIdx.x;
    const int b   = blockIdx.x >> 2;
    const int p0  = (blockIdx.x & 3) * BM;
    const int ty  = tid >> 4;
    const int tx  = tid & 15;

    const float* zbp = z + (size_t)b * NP * ND;

    vs[tid]       = view[tid];
    vs[tid + 256] = view[tid + 256];
    __syncthreads();

    int rv[8];
#pragma unroll
    for (int i = 0; i < 8; ++i) rv[i] = vs[p0 + ty * 8 + i];

    float best[8];
    int bj[8];
#pragma unroll
    for (int i = 0; i < 8; ++i) { best[i] = -1e30f; bj[i] = 0; }

    float4 pa[4], pb[2];
#pragma unroll
    for (int i = 0; i < 4; ++i) {
        int s = tid + 256 * i, r = s >> 3, kg = s & 7;
        pa[i] = *(const float4*)&zbp[(p0 + r) * ND + kg * 4];
    }
#pragma unroll
    for (int i = 0; i < 2; ++i) {
        int s = tid + 256 * i, r = s >> 3, kg = s & 7;
        pb[i] = *(const float4*)&zbp[r * ND + kg * 4];
    }

    float acc[8][4];
    for (int T = 0; T < NTILES; ++T) {
        const int kt = T % NKT;
        const int qt = T / NKT;
        if (kt == 0) {
#pragma unroll
            for (int i = 0; i < 8; ++i)
#pragma unroll
                for (int j = 0; j < 4; ++j) acc[i][j] = 0.f;
        }
        __syncthreads();
#pragma unroll
        for (int i = 0; i < 4; ++i) {
            int s = tid + 256 * i, r = s >> 3, kg = s & 7;
            As[kg * 4 + 0][r] = pa[i].x;
            As[kg * 4 + 1][r] = pa[i].y;
            As[kg * 4 + 2][r] = pa[i].z;
            As[kg * 4 + 3][r] = pa[i].w;
        }
#pragma unroll
        for (int i = 0; i < 2; ++i) {
            int s = tid + 256 * i, r = s >> 3, kg = s & 7;
            Bs[kg * 4 + 0][r] = pb[i].x;
            Bs[kg * 4 + 1][r] = pb[i].y;
            Bs[kg * 4 + 2][r] = pb[i].z;
            Bs[kg * 4 + 3][r] = pb[i].w;
        }
        if (T + 1 < NTILES) {
            const int ktn = (T + 1) % NKT;
            const int qtn = (T + 1) / NKT;
            const int k0n = ktn * BK;
            const int q0n = qtn * BN;
#pragma unroll
            for (int i = 0; i < 4; ++i) {
                int s = tid + 256 * i, r = s >> 3, kg = s & 7;
                pa[i] = *(const float4*)&zbp[(p0 + r) * ND + k0n + kg * 4];
            }
#pragma unroll
            for (int i = 0; i < 2; ++i) {
                int s = tid + 256 * i, r = s >> 3, kg = s & 7;
                pb[i] = *(const float4*)&zbp[(q0n + r) * ND + k0n + kg * 4];
            }
        }
        __syncthreads();
#pragma unroll 8
        for (int k = 0; k < BK; ++k) {
            float4 a0 = *(const float4*)&As[k][ty * 8];
            float4 a1 = *(const float4*)&As[k][ty * 8 + 4];
            float4 bv = *(const float4*)&Bs[k][tx * 4];
            float av[8] = {a0.x, a0.y, a0.z, a0.w, a1.x, a1.y, a1.z, a1.w};
            float bw[4] = {bv.x, bv.y, bv.z, bv.w};
#pragma unroll
            for (int i = 0; i < 8; ++i)
#pragma unroll
                for (int j = 0; j < 4; ++j)
                    acc[i][j] = fmaf(av[i], bw[j], acc[i][j]);
        }
        if (kt == NKT - 1) {
            const int q0f = qt * BN;
            int cv[4];
#pragma unroll
            for (int j = 0; j < 4; ++j) cv[j] = vs[q0f + tx * 4 + j];
#pragma unroll
            for (int i = 0; i < 8; ++i) {
#pragma unroll
                for (int j = 0; j < 4; ++j) {
                    float v = (cv[j] != rv[i]) ? acc[i][j] : -1.0f;
                    int q = q0f + tx * 4 + j;
                    if (v > best[i]) { best[i] = v; bj[i] = q; }
                }
            }
        }
    }
#pragma unroll
    for (int i = 0; i < 8; ++i) {
        float v = best[i];
        int id = bj[i];
#pragma unroll
        for (int off = 1; off < 16; off <<= 1) {
            float ov = __shfl_xor(v, off);
            int oi = __shfl_xor(id, off);
            if (ov > v || (ov == v && oi < id)) { v = ov; id = oi; }
        }
        if (tx == 0) {
            int p = p0 + ty * 8 + i;
            bval[b * NP + p] = v;
            bidx[b * NP + p] = b * NP + id;
        }
    }
}

// ---- Phase 2a: per-1024-chunk local top-20 ----
__global__ __launch_bounds__(256) void fm_topk_local(
    const float* __restrict__ bval, float* __restrict__ cval, int* __restrict__ cidx)
{
    __shared__ float sv[1024];
    __shared__ int   si[1024];
    __shared__ float wv[4];
    __shared__ int   wi[4];

    const int t = threadIdx.x;
    const int base = blockIdx.x * 1024;
#pragma unroll
    for (int i = 0; i < 4; ++i) {
        int e = t + 256 * i;
        sv[e] = bval[base + e];
        si[e] = base + e;
    }
    __syncthreads();

    const int lane = t & 63, w = t >> 6;
    for (int it = 0; it < NGAMMA; ++it) {
        float v = sv[t];
        int pos = t;
#pragma unroll
        for (int i = 1; i < 4; ++i) {
            int e = t + 256 * i;
            float x = sv[e];
            if (x > v || (x == v && e < pos)) { v = x; pos = e; }
        }
#pragma unroll
        for (int off = 1; off < 64; off <<= 1) {
            float ov = __shfl_xor(v, off);
            int op = __shfl_xor(pos, off);
            if (ov > v || (ov == v && op < pos)) { v = ov; pos = op; }
        }
        if (lane == 0) { wv[w] = v; wi[w] = pos; }
        __syncthreads();
        if (t == 0) {
            float bv2 = wv[0];
            int bp = wi[0];
            for (int k = 1; k < 4; ++k)
                if (wv[k] > bv2 || (wv[k] == bv2 && wi[k] < bp)) { bv2 = wv[k]; bp = wi[k]; }
            cval[blockIdx.x * NGAMMA + it] = bv2;
            cidx[blockIdx.x * NGAMMA + it] = si[bp];
            sv[bp] = -1e30f;
        }
        __syncthreads();
    }
}

// ---- Phase 2b: merge 1280 candidates -> top-20 -> loss + avg_cos ----
__global__ __launch_bounds__(256) void fm_final(
    const float* __restrict__ cval, const int* __restrict__ cidx,
    const int* __restrict__ bidx, const float* __restrict__ z,
    float* __restrict__ out)
{
    __shared__ float sv[1280];
    __shared__ int   si[1280];
    __shared__ float wv[4];
    __shared__ int   wi[4];
    __shared__ int   sel[NGAMMA];
    __shared__ float ssum;
    __shared__ float red[4];

    const int t = threadIdx.x;
    for (int e = t; e < 1280; e += 256) { sv[e] = cval[e]; si[e] = cidx[e]; }
    if (t == 0) ssum = 0.f;
    __syncthreads();

    const int lane = t & 63, w = t >> 6;
    for (int it = 0; it < NGAMMA; ++it) {
        float v = sv[t];
        int pos = t;
        for (int e = t + 256; e < 1280; e += 256) {
            float x = sv[e];
            if (x > v || (x == v && e < pos)) { v = x; pos = e; }
        }
#pragma unroll
        for (int off = 1; off < 64; off <<= 1) {
            float ov = __shfl_xor(v, off);
            int op = __shfl_xor(pos, off);
            if (ov > v || (ov == v && op < pos)) { v = ov; pos = op; }
        }
        if (lane == 0) { wv[w] = v; wi[w] = pos; }
        __syncthreads();
        if (t == 0) {
            float bv2 = wv[0];
            int bp = wi[0];
            for (int k = 1; k < 4; ++k)
                if (wv[k] > bv2 || (wv[k] == bv2 && wi[k] < bp)) { bv2 = wv[k]; bp = wi[k]; }
            sel[it] = si[bp];
            ssum += bv2;
            sv[bp] = -1e30f;
        }
        __syncthreads();
    }

    float acc = 0.f;
    for (int pr = 0; pr < NGAMMA; ++pr) {
        const int a = sel[pr];
        const int j = bidx[a];
        const float* za = z + (size_t)a * ND;
        const float* zj = z + (size_t)j * ND;
        for (int d = t; d < ND; d += 256) {
            float df = za[d] - zj[d];
            acc = fmaf(df, df, acc);
        }
    }
#pragma unroll
    for (int off = 1; off < 64; off <<= 1) acc += __shfl_xor(acc, off);
    if (lane == 0) red[w] = acc;
    __syncthreads();
    if (t == 0) {
        float tot = red[0] + red[1] + red[2] + red[3];
        out[0] = 25.0f * tot / (float)(NGAMMA * ND);
        out[1] = ssum / (float)NGAMMA;
    }
}

extern "C" void kernel_launch(void* const* d_in, const int* in_sizes, int n_in,
                              void* d_out, int out_size, void* d_ws, size_t ws_size,
                              hipStream_t stream)
{
    const float* z    = (const float*)d_in[0];
    const int*   view = (const int*)d_in[1];
    float*       out  = (float*)d_out;
    char* ws = (char*)d_ws;

    const size_t zhi_off  = 0;
    const size_t zlo_off  = (size_t)NB * NP * ND * 2;            // 50331648
    const size_t pval_off = zlo_off * 2;                         // 100663296
    const size_t pidx_off = pval_off + (size_t)NB * NP * 4 * 4;  // +1 MB
    const size_t bval_off = pidx_off + (size_t)NB * NP * 4 * 4;
    const size_t bidx_off = bval_off + (size_t)NB * NP * 4;
    const size_t cval_off = bidx_off + (size_t)NB * NP * 4;
    const size_t cidx_off = cval_off + 64 * NGAMMA * 4;
    const size_t need     = cidx_off + 64 * NGAMMA * 4;

    if (ws_size >= need) {
        unsigned short* zhi = (unsigned short*)(ws + zhi_off);
        unsigned short* zlo = (unsigned short*)(ws + zlo_off);
        float* pval = (float*)(ws + pval_off);
        int*   pidx = (int*)(ws + pidx_off);
        float* bval = (float*)(ws + bval_off);
        int*   bidx = (int*)(ws + bidx_off);
        float* cval = (float*)(ws + cval_off);
        int*   cidx = (int*)(ws + cidx_off);

        fm_convert<<<(NB * NP * ND) / (8 * 256), 256, 0, stream>>>(z, zhi, zlo);
        fm_gemm<<<NB * 16, 256, 0, stream>>>(zhi, zlo, view, pval, pidx);
        fm_combine<<<(NB * NP) / 256, 256, 0, stream>>>(pval, pidx, bval, bidx);
        fm_topk_local<<<(NB * NP) / 1024, 256, 0, stream>>>(bval, cval, cidx);
        fm_final<<<1, 256, 0, stream>>>(cval, cidx, bidx, z, out);
    } else {
        float* ws_val = (float*)ws;
        int*   ws_idx = (int*)(ws + (size_t)NB * NP * 4);
        float* cval   = (float*)(ws + (size_t)NB * NP * 8);
        int*   cidx   = (int*)(ws + (size_t)NB * NP * 8 + 64 * NGAMMA * 4);

        fm_phase1<<<NB * (NP / BM), 256, 0, stream>>>(z, view, ws_val, ws_idx);
        fm_topk_local<<<(NB * NP) / 1024, 256, 0, stream>>>(ws_val, cval, cidx);
        fm_final<<<1, 256, 0, stream>>>(cval, cidx, ws_idx, z, out);
    }
}

// Round 3
// 183.546 us; speedup vs baseline: 2.6513x; 1.1892x over previous
//
#include <hip/hip_runtime.h>

// FeatureMatchSimpleLoss: B=128, P=512, D=384, GAMMA=20, LAMBDA_INV=25
// R3: split-bf16 MFMA + symmetric tiling (10/16 tiles) + 2-phase LDS pipeline.
//   fm_convert: z(fp32) -> z_hi, z_lo (bf16 RNE split)
//   fm_gemm:    per (b, upper-tri 128x128 tile): S = A*B^T via 3 MFMA products,
//               double-buffered staging (STAGE(next) -> compute(cur) -> barrier),
//               fused masked row-side AND col-side max/argmax partials
//   fm_combine: merge 4 column-block partials per (b,p)
//   fm_topk_local / fm_final: global top-20 -> loss, avg cos
// Fallback to fp32 VALU path if ws_size too small.

#define NB 128
#define NP 512
#define ND 384
#define NGAMMA 20
#define NKS 12   // 384/32 k-steps

typedef __attribute__((ext_vector_type(8))) short short8;
typedef __attribute__((ext_vector_type(4))) float f32x4;

__device__ __forceinline__ unsigned short f2bf(float f) {
    unsigned int u = __float_as_uint(f);
    u += 0x7fffu + ((u >> 16) & 1u);   // RNE
    return (unsigned short)(u >> 16);
}
__device__ __forceinline__ float bf2f(unsigned short h) {
    return __uint_as_float(((unsigned int)h) << 16);
}

__device__ __forceinline__ void gload16(const void* gptr, void* lptr) {
    __builtin_amdgcn_global_load_lds(
        (const __attribute__((address_space(1))) void*)gptr,
        (__attribute__((address_space(3))) void*)lptr, 16, 0, 0);
}

// ---- convert: 8 floats/thread -> 8 bf16 hi + 8 bf16 lo ----
__global__ __launch_bounds__(256) void fm_convert(
    const float* __restrict__ z, unsigned short* __restrict__ zhi,
    unsigned short* __restrict__ zlo)
{
    size_t i = (size_t)blockIdx.x * 256 + threadIdx.x;
    const float4* zp = (const float4*)z + i * 2;
    float4 v0 = zp[0], v1 = zp[1];
    float f[8] = {v0.x, v0.y, v0.z, v0.w, v1.x, v1.y, v1.z, v1.w};
    unsigned short h[8], lo[8];
#pragma unroll
    for (int j = 0; j < 8; ++j) {
        h[j]  = f2bf(f[j]);
        lo[j] = f2bf(f[j] - bf2f(h[j]));
    }
    *(ushort4*)&zhi[i * 8]     = make_ushort4(h[0], h[1], h[2], h[3]);
    *(ushort4*)&zhi[i * 8 + 4] = make_ushort4(h[4], h[5], h[6], h[7]);
    *(ushort4*)&zlo[i * 8]     = make_ushort4(lo[0], lo[1], lo[2], lo[3]);
    *(ushort4*)&zlo[i * 8 + 4] = make_ushort4(lo[4], lo[5], lo[6], lo[7]);
}

// ---- MFMA GEMM on upper-triangle tiles + fused masked max/argmax ----
__global__ __launch_bounds__(256) void fm_gemm(
    const unsigned short* __restrict__ zhi, const unsigned short* __restrict__ zlo,
    const int* __restrict__ view,
    float* __restrict__ pval, int* __restrict__ pidx)
{
    // double-buffered [sel][kg][row][8] bf16 tiles: staging writes linear
    // (wave-uniform base + lane*16), ds_read_b128 frag reads conflict-free.
    __shared__ __align__(16) unsigned short Ah[2][4][128][8];
    __shared__ __align__(16) unsigned short Al[2][4][128][8];
    __shared__ __align__(16) unsigned short Bh[2][4][128][8];
    __shared__ __align__(16) unsigned short Bl[2][4][128][8];
    __shared__ int vs[NP];
    __shared__ float lsv[2][2][64];   // row-side [wr][wc][row]
    __shared__ int   lsi[2][2][64];
    __shared__ float lqv[2][2][64];   // col-side [wc][wr][col]
    __shared__ int   lqi[2][2][64];

    const int tid  = threadIdx.x;
    const int lane = tid & 63;
    const int wid  = tid >> 6;
    const int wr   = wid >> 1, wc = wid & 1;
    const int g    = lane >> 4, r = lane & 15;

    // XCD swizzle (1280 % 8 == 0 -> bijective): each XCD gets 16 consecutive batches
    const int bid = blockIdx.x;
    const int gidx = (bid & 7) * 160 + (bid >> 3);   // 0..1279
    const int b  = gidx / 10;
    const int t  = gidx % 10;
    int tr, tc;
    if (t < 4)      { tr = 0; tc = t; }
    else if (t < 7) { tr = 1; tc = t - 3; }
    else if (t < 9) { tr = 2; tc = t - 5; }
    else            { tr = 3; tc = 3; }
    const bool diag = (tr == tc);
    const int p0 = tr * 128, q0 = tc * 128;

    vs[tid]       = view[tid];
    vs[tid + 256] = view[tid + 256];

    const size_t zb = (size_t)b * NP * ND;

    f32x4 acc[4][4];
#pragma unroll
    for (int mi = 0; mi < 4; ++mi)
#pragma unroll
        for (int ni = 0; ni < 4; ++ni) acc[mi][ni] = (f32x4){0.f, 0.f, 0.f, 0.f};

#define STAGE(SEL, KTV)                                                          \
    do {                                                                         \
        _Pragma("unroll")                                                        \
        for (int ci = 0; ci < 2; ++ci) {                                         \
            const int c_  = wid * 2 + ci;                                        \
            const int kg_ = c_ >> 1;                                             \
            const int rh_ = (c_ & 1) * 64;                                       \
            const size_t ea_ = zb + (size_t)(p0 + rh_ + lane) * ND + (KTV) * 32 + kg_ * 8; \
            gload16(zhi + ea_, &Ah[SEL][kg_][rh_][0]);                           \
            gload16(zlo + ea_, &Al[SEL][kg_][rh_][0]);                           \
            if (!diag) {                                                         \
                const size_t eb_ = zb + (size_t)(q0 + rh_ + lane) * ND + (KTV) * 32 + kg_ * 8; \
                gload16(zhi + eb_, &Bh[SEL][kg_][rh_][0]);                       \
                gload16(zlo + eb_, &Bl[SEL][kg_][rh_][0]);                       \
            }                                                                    \
        }                                                                        \
    } while (0)

#define KSTEP(CUR, KTV)                                                          \
    do {                                                                         \
        if ((KTV) + 1 < NKS) STAGE((CUR) ^ 1, (KTV) + 1);                        \
        short8 ah_[4], al_[4], bh_[4], bl_[4];                                   \
        _Pragma("unroll")                                                        \
        for (int mi = 0; mi < 4; ++mi) {                                         \
            ah_[mi] = *(const short8*)&Ah[CUR][g][wr * 64 + mi * 16 + r][0];     \
            al_[mi] = *(const short8*)&Al[CUR][g][wr * 64 + mi * 16 + r][0];     \
        }                                                                        \
        _Pragma("unroll")                                                        \
        for (int ni = 0; ni < 4; ++ni) {                                         \
            const int rw_ = wc * 64 + ni * 16 + r;                               \
            bh_[ni] = diag ? *(const short8*)&Ah[CUR][g][rw_][0]                 \
                           : *(const short8*)&Bh[CUR][g][rw_][0];                \
            bl_[ni] = diag ? *(const short8*)&Al[CUR][g][rw_][0]                 \
                           : *(const short8*)&Bl[CUR][g][rw_][0];                \
        }                                                                        \
        _Pragma("unroll")                                                        \
        for (int mi = 0; mi < 4; ++mi)                                           \
            _Pragma("unroll")                                                    \
            for (int ni = 0; ni < 4; ++ni) {                                     \
                acc[mi][ni] = __builtin_amdgcn_mfma_f32_16x16x32_bf16(ah_[mi], bh_[ni], acc[mi][ni], 0, 0, 0); \
                acc[mi][ni] = __builtin_amdgcn_mfma_f32_16x16x32_bf16(ah_[mi], bl_[ni], acc[mi][ni], 0, 0, 0); \
                acc[mi][ni] = __builtin_amdgcn_mfma_f32_16x16x32_bf16(al_[mi], bh_[ni], acc[mi][ni], 0, 0, 0); \
            }                                                                    \
        __syncthreads();                                                         \
    } while (0)

    STAGE(0, 0);
    __syncthreads();   // drains stage-0 loads; vs[] visible
    for (int kt = 0; kt < NKS; kt += 2) {
        KSTEP(0, kt);
        KSTEP(1, kt + 1);
    }

    // ---- row-side: per row p, masked max/argmax over this tile's 128 cols ----
    // C/D layout: col = lane&15 (r), row = (lane>>4)*4 + j (g,j)
#pragma unroll
    for (int mi = 0; mi < 4; ++mi) {
#pragma unroll
        for (int j = 0; j < 4; ++j) {
            const int prow = p0 + wr * 64 + mi * 16 + g * 4 + j;
            const int rv = vs[prow];
            float bv = -2.0f; int bq = 0;
#pragma unroll
            for (int ni = 0; ni < 4; ++ni) {   // ascending q; strict > keeps smallest
                const int q = q0 + wc * 64 + ni * 16 + r;
                const float v = (vs[q] != rv) ? acc[mi][ni][j] : -1.0f;
                if (v > bv) { bv = v; bq = q; }
            }
#pragma unroll
            for (int off = 1; off < 16; off <<= 1) {   // reduce over col-lanes
                const float ov = __shfl_xor(bv, off);
                const int   oq = __shfl_xor(bq, off);
                if (ov > bv || (ov == bv && oq < bq)) { bv = ov; bq = oq; }
            }
            if (r == 0) {
                lsv[wr][wc][mi * 16 + g * 4 + j] = bv;
                lsi[wr][wc][mi * 16 + g * 4 + j] = bq;
            }
        }
    }
    // ---- col-side (off-diag only): per col q, masked max/argmax over 128 rows ----
    if (!diag) {
#pragma unroll
        for (int ni = 0; ni < 4; ++ni) {
            const int q = q0 + wc * 64 + ni * 16 + r;
            const int qv = vs[q];
            float bv = -2.0f; int bp = 0;
#pragma unroll
            for (int mi = 0; mi < 4; ++mi)
#pragma unroll
                for (int j = 0; j < 4; ++j) {   // ascending p within fixed g
                    const int prow = p0 + wr * 64 + mi * 16 + g * 4 + j;
                    const float v = (vs[prow] != qv) ? acc[mi][ni][j] : -1.0f;
                    if (v > bv) { bv = v; bp = prow; }
                }
#pragma unroll
            for (int off = 16; off < 64; off <<= 1) {   // reduce over g groups
                const float ov = __shfl_xor(bv, off);
                const int   op = __shfl_xor(bp, off);
                if (ov > bv || (ov == bv && op < bp)) { bv = ov; bp = op; }
            }
            if (g == 0) {
                lqv[wc][wr][ni * 16 + r] = bv;
                lqi[wc][wr][ni * 16 + r] = bp;
            }
        }
    }
    __syncthreads();
    if (tid < 128) {
        const int half = tid >> 6, row = tid & 63;
        {
            float v0 = lsv[half][0][row]; int i0 = lsi[half][0][row];
            const float v1 = lsv[half][1][row]; const int i1 = lsi[half][1][row];
            if (v1 > v0) { v0 = v1; i0 = i1; }   // tie keeps wc=0 (smaller q)
            const int p = p0 + half * 64 + row;
            pval[((size_t)b * NP + p) * 4 + tc] = v0;
            pidx[((size_t)b * NP + p) * 4 + tc] = i0;
        }
        if (!diag) {
            float v0 = lqv[half][0][row]; int i0 = lqi[half][0][row];
            const float v1 = lqv[half][1][row]; const int i1 = lqi[half][1][row];
            if (v1 > v0) { v0 = v1; i0 = i1; }   // tie keeps wr=0 (smaller p)
            const int q = q0 + half * 64 + row;
            pval[((size_t)b * NP + q) * 4 + tr] = v0;
            pidx[((size_t)b * NP + q) * 4 + tr] = i0;
        }
    }
#undef STAGE
#undef KSTEP
}

// ---- combine 4 column-block partials per (b,p) ----
__global__ __launch_bounds__(256) void fm_combine(
    const float* __restrict__ pval, const int* __restrict__ pidx,
    float* __restrict__ bval, int* __restrict__ bidx)
{
    const int i = blockIdx.x * 256 + threadIdx.x;   // 65536
    float bv = -2.f; int bq = 0;
#pragma unroll
    for (int c = 0; c < 4; ++c) {   // ascending q-blocks; strict > keeps first
        const float v = pval[(size_t)i * 4 + c];
        const int q = pidx[(size_t)i * 4 + c];
        if (v > bv) { bv = v; bq = q; }
    }
    bval[i] = bv;
    bidx[i] = ((i >> 9) << 9) + bq;   // flat b*512 + q
}

// ---- R1 fp32 fallback phase 1 (used only if ws too small) ----
#define BM 128
#define BN 64
#define BK 32
#define NQT (NP / BN)
#define NKT (ND / BK)
#define NTILES (NQT * NKT)

__global__ __launch_bounds__(256) void fm_phase1(
    const float* __restrict__ z, const int* __restrict__ view,
    float* __restrict__ bval, int* __restrict__ bidx)
{
    __shared__ __align__(16) float As[BK][BM + 4];
    __shared__ __align__(16) float Bs[BK][BN + 4];
    __shared__ int vs[NP];

    const int tid = threadIdx.x;
    const int b   = blockIdx.x >> 2;
    const int p0  = (blockIdx.x & 3) * BM;
    const int ty  = tid >> 4;
    const int tx  = tid & 15;

    const float* zbp = z + (size_t)b * NP * ND;

    vs[tid]       = view[tid];
    vs[tid + 256] = view[tid + 256];
    __syncthreads();

    int rv[8];
#pragma unroll
    for (int i = 0; i < 8; ++i) rv[i] = vs[p0 + ty * 8 + i];

    float best[8];
    int bj[8];
#pragma unroll
    for (int i = 0; i < 8; ++i) { best[i] = -1e30f; bj[i] = 0; }

    float4 pa[4], pb[2];
#pragma unroll
    for (int i = 0; i < 4; ++i) {
        int s = tid + 256 * i, rr = s >> 3, kg = s & 7;
        pa[i] = *(const float4*)&zbp[(p0 + rr) * ND + kg * 4];
    }
#pragma unroll
    for (int i = 0; i < 2; ++i) {
        int s = tid + 256 * i, rr = s >> 3, kg = s & 7;
        pb[i] = *(const float4*)&zbp[rr * ND + kg * 4];
    }

    float acc[8][4];
    for (int T = 0; T < NTILES; ++T) {
        const int kt = T % NKT;
        const int qt = T / NKT;
        if (kt == 0) {
#pragma unroll
            for (int i = 0; i < 8; ++i)
#pragma unroll
                for (int j = 0; j < 4; ++j) acc[i][j] = 0.f;
        }
        __syncthreads();
#pragma unroll
        for (int i = 0; i < 4; ++i) {
            int s = tid + 256 * i, rr = s >> 3, kg = s & 7;
            As[kg * 4 + 0][rr] = pa[i].x;
            As[kg * 4 + 1][rr] = pa[i].y;
            As[kg * 4 + 2][rr] = pa[i].z;
            As[kg * 4 + 3][rr] = pa[i].w;
        }
#pragma unroll
        for (int i = 0; i < 2; ++i) {
            int s = tid + 256 * i, rr = s >> 3, kg = s & 7;
            Bs[kg * 4 + 0][rr] = pb[i].x;
            Bs[kg * 4 + 1][rr] = pb[i].y;
            Bs[kg * 4 + 2][rr] = pb[i].z;
            Bs[kg * 4 + 3][rr] = pb[i].w;
        }
        if (T + 1 < NTILES) {
            const int ktn = (T + 1) % NKT;
            const int qtn = (T + 1) / NKT;
            const int k0n = ktn * BK;
            const int q0n = qtn * BN;
#pragma unroll
            for (int i = 0; i < 4; ++i) {
                int s = tid + 256 * i, rr = s >> 3, kg = s & 7;
                pa[i] = *(const float4*)&zbp[(p0 + rr) * ND + k0n + kg * 4];
            }
#pragma unroll
            for (int i = 0; i < 2; ++i) {
                int s = tid + 256 * i, rr = s >> 3, kg = s & 7;
                pb[i] = *(const float4*)&zbp[(q0n + rr) * ND + k0n + kg * 4];
            }
        }
        __syncthreads();
#pragma unroll 8
        for (int k = 0; k < BK; ++k) {
            float4 a0 = *(const float4*)&As[k][ty * 8];
            float4 a1 = *(const float4*)&As[k][ty * 8 + 4];
            float4 bv = *(const float4*)&Bs[k][tx * 4];
            float av[8] = {a0.x, a0.y, a0.z, a0.w, a1.x, a1.y, a1.z, a1.w};
            float bw[4] = {bv.x, bv.y, bv.z, bv.w};
#pragma unroll
            for (int i = 0; i < 8; ++i)
#pragma unroll
                for (int j = 0; j < 4; ++j)
                    acc[i][j] = fmaf(av[i], bw[j], acc[i][j]);
        }
        if (kt == NKT - 1) {
            const int q0f = qt * BN;
            int cv[4];
#pragma unroll
            for (int j = 0; j < 4; ++j) cv[j] = vs[q0f + tx * 4 + j];
#pragma unroll
            for (int i = 0; i < 8; ++i) {
#pragma unroll
                for (int j = 0; j < 4; ++j) {
                    float v = (cv[j] != rv[i]) ? acc[i][j] : -1.0f;
                    int q = q0f + tx * 4 + j;
                    if (v > best[i]) { best[i] = v; bj[i] = q; }
                }
            }
        }
    }
#pragma unroll
    for (int i = 0; i < 8; ++i) {
        float v = best[i];
        int id = bj[i];
#pragma unroll
        for (int off = 1; off < 16; off <<= 1) {
            float ov = __shfl_xor(v, off);
            int oi = __shfl_xor(id, off);
            if (ov > v || (ov == v && oi < id)) { v = ov; id = oi; }
        }
        if (tx == 0) {
            int p = p0 + ty * 8 + i;
            bval[b * NP + p] = v;
            bidx[b * NP + p] = b * NP + id;
        }
    }
}

// ---- Phase 2a: per-1024-chunk local top-20 ----
__global__ __launch_bounds__(256) void fm_topk_local(
    const float* __restrict__ bval, float* __restrict__ cval, int* __restrict__ cidx)
{
    __shared__ float sv[1024];
    __shared__ int   si[1024];
    __shared__ float wv[4];
    __shared__ int   wi[4];

    const int t = threadIdx.x;
    const int base = blockIdx.x * 1024;
#pragma unroll
    for (int i = 0; i < 4; ++i) {
        int e = t + 256 * i;
        sv[e] = bval[base + e];
        si[e] = base + e;
    }
    __syncthreads();

    const int lane = t & 63, w = t >> 6;
    for (int it = 0; it < NGAMMA; ++it) {
        float v = sv[t];
        int pos = t;
#pragma unroll
        for (int i = 1; i < 4; ++i) {
            int e = t + 256 * i;
            float x = sv[e];
            if (x > v || (x == v && e < pos)) { v = x; pos = e; }
        }
#pragma unroll
        for (int off = 1; off < 64; off <<= 1) {
            float ov = __shfl_xor(v, off);
            int op = __shfl_xor(pos, off);
            if (ov > v || (ov == v && op < pos)) { v = ov; pos = op; }
        }
        if (lane == 0) { wv[w] = v; wi[w] = pos; }
        __syncthreads();
        if (t == 0) {
            float bv2 = wv[0];
            int bp = wi[0];
            for (int k = 1; k < 4; ++k)
                if (wv[k] > bv2 || (wv[k] == bv2 && wi[k] < bp)) { bv2 = wv[k]; bp = wi[k]; }
            cval[blockIdx.x * NGAMMA + it] = bv2;
            cidx[blockIdx.x * NGAMMA + it] = si[bp];
            sv[bp] = -1e30f;
        }
        __syncthreads();
    }
}

// ---- Phase 2b: merge 1280 candidates -> top-20 -> loss + avg_cos ----
__global__ __launch_bounds__(256) void fm_final(
    const float* __restrict__ cval, const int* __restrict__ cidx,
    const int* __restrict__ bidx, const float* __restrict__ z,
    float* __restrict__ out)
{
    __shared__ float sv[1280];
    __shared__ int   si[1280];
    __shared__ float wv[4];
    __shared__ int   wi[4];
    __shared__ int   sel[NGAMMA];
    __shared__ float ssum;
    __shared__ float red[4];

    const int t = threadIdx.x;
    for (int e = t; e < 1280; e += 256) { sv[e] = cval[e]; si[e] = cidx[e]; }
    if (t == 0) ssum = 0.f;
    __syncthreads();

    const int lane = t & 63, w = t >> 6;
    for (int it = 0; it < NGAMMA; ++it) {
        float v = sv[t];
        int pos = t;
        for (int e = t + 256; e < 1280; e += 256) {
            float x = sv[e];
            if (x > v || (x == v && e < pos)) { v = x; pos = e; }
        }
#pragma unroll
        for (int off = 1; off < 64; off <<= 1) {
            float ov = __shfl_xor(v, off);
            int op = __shfl_xor(pos, off);
            if (ov > v || (ov == v && op < pos)) { v = ov; pos = op; }
        }
        if (lane == 0) { wv[w] = v; wi[w] = pos; }
        __syncthreads();
        if (t == 0) {
            float bv2 = wv[0];
            int bp = wi[0];
            for (int k = 1; k < 4; ++k)
                if (wv[k] > bv2 || (wv[k] == bv2 && wi[k] < bp)) { bv2 = wv[k]; bp = wi[k]; }
            sel[it] = si[bp];
            ssum += bv2;
            sv[bp] = -1e30f;
        }
        __syncthreads();
    }

    float acc = 0.f;
    for (int pr = 0; pr < NGAMMA; ++pr) {
        const int a = sel[pr];
        const int j = bidx[a];
        const float* za = z + (size_t)a * ND;
        const float* zj = z + (size_t)j * ND;
        for (int d = t; d < ND; d += 256) {
            float df = za[d] - zj[d];
            acc = fmaf(df, df, acc);
        }
    }
#pragma unroll
    for (int off = 1; off < 64; off <<= 1) acc += __shfl_xor(acc, off);
    if (lane == 0) red[w] = acc;
    __syncthreads();
    if (t == 0) {
        float tot = red[0] + red[1] + red[2] + red[3];
        out[0] = 25.0f * tot / (float)(NGAMMA * ND);
        out[1] = ssum / (float)NGAMMA;
    }
}

extern "C" void kernel_launch(void* const* d_in, const int* in_sizes, int n_in,
                              void* d_out, int out_size, void* d_ws, size_t ws_size,
                              hipStream_t stream)
{
    const float* z    = (const float*)d_in[0];
    const int*   view = (const int*)d_in[1];
    float*       out  = (float*)d_out;
    char* ws = (char*)d_ws;

    const size_t zhi_off  = 0;
    const size_t zlo_off  = (size_t)NB * NP * ND * 2;
    const size_t pval_off = zlo_off * 2;
    const size_t pidx_off = pval_off + (size_t)NB * NP * 4 * 4;
    const size_t bval_off = pidx_off + (size_t)NB * NP * 4 * 4;
    const size_t bidx_off = bval_off + (size_t)NB * NP * 4;
    const size_t cval_off = bidx_off + (size_t)NB * NP * 4;
    const size_t cidx_off = cval_off + 64 * NGAMMA * 4;
    const size_t need     = cidx_off + 64 * NGAMMA * 4;

    if (ws_size >= need) {
        unsigned short* zhi = (unsigned short*)(ws + zhi_off);
        unsigned short* zlo = (unsigned short*)(ws + zlo_off);
        float* pval = (float*)(ws + pval_off);
        int*   pidx = (int*)(ws + pidx_off);
        float* bval = (float*)(ws + bval_off);
        int*   bidx = (int*)(ws + bidx_off);
        float* cval = (float*)(ws + cval_off);
        int*   cidx = (int*)(ws + cidx_off);

        fm_convert<<<(NB * NP * ND) / (8 * 256), 256, 0, stream>>>(z, zhi, zlo);
        fm_gemm<<<NB * 10, 256, 0, stream>>>(zhi, zlo, view, pval, pidx);
        fm_combine<<<(NB * NP) / 256, 256, 0, stream>>>(pval, pidx, bval, bidx);
        fm_topk_local<<<(NB * NP) / 1024, 256, 0, stream>>>(bval, cval, cidx);
        fm_final<<<1, 256, 0, stream>>>(cval, cidx, bidx, z, out);
    } else {
        float* ws_val = (float*)ws;
        int*   ws_idx = (int*)(ws + (size_t)NB * NP * 4);
        float* cval   = (float*)(ws + (size_t)NB * NP * 8);
        int*   cidx   = (int*)(ws + (size_t)NB * NP * 8 + 64 * NGAMMA * 4);

        fm_phase1<<<NB * (NP / BM), 256, 0, stream>>>(z, view, ws_val, ws_idx);
        fm_topk_local<<<(NB * NP) / 1024, 256, 0, stream>>>(ws_val, cval, cidx);
        fm_final<<<1, 256, 0, stream>>>(cval, cidx, ws_idx, z, out);
    }
}